// Round 12
// baseline (434.450 us; speedup 1.0000x reference)
//
#include <hip/hip_runtime.h>
#include <hip/hip_bf16.h>

#define DEV __device__ __forceinline__

typedef unsigned short u16;
typedef unsigned int u32;
typedef float f32x4 __attribute__((ext_vector_type(4)));
typedef short s16x8 __attribute__((ext_vector_type(8)));

static constexpr int Bb = 4, Ll = 2048, DM = 1024, DI = 2048, NH = 32;
static constexpr int CD = 2304;       // conv dim
static constexpr int NP = 4384;       // d_in_proj
static constexpr int NP_PAD = 4480;   // 35*128
static constexpr int BL = Bb * Ll;    // 8192
static constexpr int NC = 32;         // chunks per sequence (L/64)

DEV float u2f(u16 s) { return __uint_as_float(((u32)s) << 16); }
DEV u16 f2bu(float f) {
  __hip_bfloat16 h = __float2bfloat16(f);
  u16 s; __builtin_memcpy(&s, &h, 2); return s;
}
DEV float blo(u32 u) { return __uint_as_float(u << 16); }
DEV float bhi(u32 u) { return __uint_as_float(u & 0xffff0000u); }

// XOR-swizzled LDS index for [rows][64] bf16 tiles (k-minor).
DEV int swz64(int r, int k)  { return r * 64  + ((((k >> 3) ^ (r & 7))) << 3) + (k & 7); }

DEV void gl_lds16(const u16* g, u16* l) {
  __builtin_amdgcn_global_load_lds(
      (const __attribute__((address_space(1))) u32*)g,
      (__attribute__((address_space(3))) u32*)l, 16, 0, 0);
}

// causal conv(4)+SiLU for 8 consecutive channels at col0, sequence pos within batch b.
DEV void conv8(const u16* __restrict__ xbcb, int pos, int col0,
               const float* __restrict__ cw, const float* __restrict__ cb,
               float* out) {
  uint4 r[4];
  #pragma unroll
  for (int k = 0; k < 4; k++) {
    int ls = pos - 3 + k;
    if (ls >= 0) r[k] = *(const uint4*)(xbcb + (size_t)ls * CD + col0);
    else         r[k] = (uint4){0u, 0u, 0u, 0u};
  }
  #pragma unroll
  for (int e = 0; e < 8; e++) {
    float acc = cb[col0 + e];
    float4 wv = *(const float4*)(cw + (size_t)(col0 + e) * 4);
    float wk[4] = {wv.x, wv.y, wv.z, wv.w};
    #pragma unroll
    for (int k = 0; k < 4; k++) {
      u32 word = (&r[k].x)[e >> 1];
      acc += wk[k] * ((e & 1) ? bhi(word) : blo(word));
    }
    float sg = 1.f / (1.f + __expf(-acc));
    out[e] = acc * sg;
  }
}

// inclusive wave-64 prefix sum
DEV float wave_scan(float a, int lane) {
  float s = a;
  #pragma unroll
  for (int o = 1; o < 64; o <<= 1) {
    float u = __shfl_up(s, o);
    if (lane >= o) s += u;
  }
  return s;
}

// ---------------- prep: LayerNorm (blocks 0..8191) + weight cvt (rest) ----------------
__global__ __launch_bounds__(256) void prep_kernel(const float* __restrict__ x,
    const float* __restrict__ w, const float* __restrict__ bia, u16* __restrict__ u,
    const float* __restrict__ w1, u16* __restrict__ W1b,
    const float* __restrict__ w2, u16* __restrict__ W2b) {
  __shared__ float rs[4], rs2[4];
  int tid = threadIdx.x;
  if (blockIdx.x < BL) {
    int row = blockIdx.x;
    const float4* xr = (const float4*)(x + (size_t)row * DM);
    float4 v = xr[tid];
    float s = v.x + v.y + v.z + v.w;
    float s2 = v.x*v.x + v.y*v.y + v.z*v.z + v.w*v.w;
    #pragma unroll
    for (int o = 32; o; o >>= 1) { s += __shfl_down(s, o); s2 += __shfl_down(s2, o); }
    int wv = tid >> 6, ln = tid & 63;
    if (ln == 0) { rs[wv] = s; rs2[wv] = s2; }
    __syncthreads();
    s = rs[0] + rs[1] + rs[2] + rs[3];
    s2 = rs2[0] + rs2[1] + rs2[2] + rs2[3];
    float mu = s * (1.f / DM);
    float var = s2 * (1.f / DM) - mu * mu;
    float inv = rsqrtf(var + 1e-5f);
    float4 wv4 = ((const float4*)w)[tid], bv4 = ((const float4*)bia)[tid];
    ushort4 o;
    o.x = f2bu((v.x - mu) * inv * wv4.x + bv4.x);
    o.y = f2bu((v.y - mu) * inv * wv4.y + bv4.y);
    o.z = f2bu((v.z - mu) * inv * wv4.z + bv4.z);
    o.w = f2bu((v.w - mu) * inv * wv4.w + bv4.w);
    ((ushort4*)(u + (size_t)row * DM))[tid] = o;
  } else {
    const int total1 = NP_PAD * 1024;
    int i = (blockIdx.x - BL) * 256 + tid;
    if (i < total1) {
      int r = i >> 10;
      W1b[i] = (r < NP) ? f2bu(w1[i]) : (u16)0;
    } else {
      int j = i - total1;
      if (j < 1024 * 2048) W2b[j] = f2bu(w2[j]);
    }
  }
}

// ============ 256x128 2-phase swizzled GEMM, counted-vmcnt prefetch ============
template<int MODE>
__global__ __launch_bounds__(512, 4) void gemm2p(const u16* __restrict__ A,
    const u16* __restrict__ Bw, void* __restrict__ o0, u16* __restrict__ xbc,
    u16* __restrict__ dtraw, const float* __restrict__ resid) {
  constexpr int K = (MODE == 0) ? 1024 : 2048;
  constexpr int NT = K / 32;
  __shared__ u16 SH[24576];
  int tid = threadIdx.x, wid = tid >> 6, lane = tid & 63;
  int fr = lane & 15, fq = lane >> 4;
  int nb = blockIdx.x;
  int xcd = nb & 7, i = nb >> 3;
  int m0 = (xcd * 4 + (i & 3)) * 256;
  int n0 = (i >> 2) * 128;
  int wm = (wid >> 1) * 64, wn = (wid & 1) * 64;
  int ksrcE = (((lane & 3) ^ ((lane >> 3) & 3)) << 3);
  int lr = lane >> 2;

  f32x4 acc[4][4];
  #pragma unroll
  for (int a = 0; a < 4; a++)
    #pragma unroll
    for (int b = 0; b < 4; b++) acc[a][b] = (f32x4){0.f, 0.f, 0.f, 0.f};

  auto STGA = [&](int t, int dstE) {
    #pragma unroll
    for (int h = 0; h < 2; h++) {
      int r0 = h * 128 + wid * 16;
      gl_lds16(A + (size_t)(m0 + r0 + lr) * K + t * 32 + ksrcE, &SH[dstE + r0 * 32]);
    }
  };
  auto STGB = [&](int t, int dstE) {
    int r0 = wid * 16;
    gl_lds16(Bw + (size_t)(n0 + r0 + lr) * K + t * 32 + ksrcE, &SH[dstE + r0 * 32]);
  };

  STGA(0, 0);
  STGB(0, 16384);
  asm volatile("s_waitcnt vmcnt(0)\n\ts_barrier" ::: "memory");
  for (int t = 0; t < NT; t++) {
    int ca = (t & 1) * 8192, cbf = 16384 + (t & 1) * 4096;
    if (t < NT - 1) {
      STGA(t + 1, ((t + 1) & 1) * 8192);
      STGB(t + 1, 16384 + ((t + 1) & 1) * 4096);
      asm volatile("s_waitcnt vmcnt(3)\n\ts_barrier" ::: "memory");
    } else {
      asm volatile("s_waitcnt vmcnt(0)\n\ts_barrier" ::: "memory");
    }
    s16x8 bB[4];
    #pragma unroll
    for (int nf = 0; nf < 4; nf++) {
      int rb = wn + nf * 16 + fr;
      bB[nf] = *(const s16x8*)&SH[cbf + rb * 32 + ((fq ^ ((rb >> 1) & 3)) << 3)];
    }
    __builtin_amdgcn_s_setprio(1);
    #pragma unroll
    for (int mf = 0; mf < 4; mf++) {
      int ra = wm + mf * 16 + fr;
      s16x8 af = *(const s16x8*)&SH[ca + ra * 32 + ((fq ^ ((ra >> 1) & 3)) << 3)];
      #pragma unroll
      for (int nf = 0; nf < 4; nf++)
        acc[mf][nf] = __builtin_amdgcn_mfma_f32_16x16x32_bf16(af, bB[nf], acc[mf][nf], 0, 0, 0);
    }
    __builtin_amdgcn_s_setprio(0);
    asm volatile("s_barrier" ::: "memory");
  }
  if (MODE == 0) {
    u16* zbuf = (u16*)o0;
    #pragma unroll
    for (int mf = 0; mf < 4; mf++) {
      #pragma unroll
      for (int nf = 0; nf < 4; nf++) {
        int col = n0 + wn + nf * 16 + fr;
        #pragma unroll
        for (int r = 0; r < 4; r++) {
          int row = m0 + wm + mf * 16 + fq * 4 + r;
          float v = acc[mf][nf][r];
          if (col < 2048)       zbuf[(size_t)row * 2048 + col] = f2bu(v);
          else if (col < 4352)  xbc[(size_t)row * 2304 + (col - 2048)] = f2bu(v);
          else if (col < 4384)  dtraw[(size_t)row * 32 + (col - 4352)] = f2bu(v);
        }
      }
    }
  } else {
    float* of = (float*)o0;
    #pragma unroll
    for (int mf = 0; mf < 4; mf++) {
      #pragma unroll
      for (int nf = 0; nf < 4; nf++) {
        int col = n0 + wn + nf * 16 + fr;
        #pragma unroll
        for (int r = 0; r < 4; r++) {
          int row = m0 + wm + mf * 16 + fq * 4 + r;
          of[(size_t)row * 1024 + col] = acc[mf][nf][r] + resid[(size_t)row * 1024 + col];
        }
      }
    }
  }
}

// ---------------- per-(b,c,h): inline conv+scan, chunk-state GEMM -> S_c (bf16) ----------------
__global__ __launch_bounds__(256) void chunk_state(const u16* __restrict__ xbc,
    const u16* __restrict__ dtraw, const float* __restrict__ dtb,
    const float* __restrict__ alog, const float* __restrict__ cw,
    const float* __restrict__ cb, u16* __restrict__ S, float* __restrict__ Etot) {
  __shared__ u16 xsT[64 * 64];   // [p][j] swizzled, scaled
  __shared__ u16 BT[128 * 64];   // [n][j] swizzled
  int gid = blockIdx.x;          // (b*32 + c)*32 + h
  int h = gid & 31, c = (gid >> 5) & 31, b = gid >> 10;
  int bh = b * 32 + h;
  int tid = threadIdx.x, w = tid >> 6, lane = tid & 63;
  int fr = lane & 15, fq = lane >> 4;
  int j = tid & 63, pg = tid >> 6;
  int tb = c * 64;
  const u16* xbcb = xbc + (size_t)b * Ll * CD;
  // inline dt scan (per-wave redundant; j == lane)
  float raw = u2f(dtraw[(size_t)(b * Ll + tb + j) * 32 + h]);
  float v = raw + dtb[h];
  float dt = (v > 20.f) ? v : log1pf(__expf(v));
  float a = -dt * __expf(alog[h]);
  float s = wave_scan(a, j);
  float s_last = __shfl(s, 63);
  float wj = __expf(s_last - s) * dt;
  if (tid == 0) Etot[(size_t)bh * NC + c] = s_last;
  // stage scaled x^T (conv inline)
  float o8[8];
  #pragma unroll
  for (int rep = 0; rep < 2; rep++) {
    int p0 = rep * 32 + pg * 8;
    conv8(xbcb, tb + j, h * 64 + p0, cw, cb, o8);
    #pragma unroll
    for (int m = 0; m < 8; m++) xsT[swz64(p0 + m, j)] = f2bu(o8[m] * wj);
  }
  // stage B^T (conv inline)
  #pragma unroll
  for (int rep = 0; rep < 4; rep++) {
    int n0 = rep * 32 + pg * 8;
    conv8(xbcb, tb + j, 2048 + n0, cw, cb, o8);
    #pragma unroll
    for (int m = 0; m < 8; m++) BT[swz64(n0 + m, j)] = f2bu(o8[m]);
  }
  __syncthreads();
  f32x4 acc[4][2];
  #pragma unroll
  for (int mi = 0; mi < 4; mi++)
    #pragma unroll
    for (int ni = 0; ni < 2; ni++) acc[mi][ni] = (f32x4){0.f, 0.f, 0.f, 0.f};
  #pragma unroll
  for (int ks = 0; ks < 2; ks++) {
    int k8 = ks * 4 + fq;
    s16x8 bfv[2];
    #pragma unroll
    for (int ni = 0; ni < 2; ni++) {
      int rb = w * 32 + ni * 16 + fr;
      bfv[ni] = *(const s16x8*)&BT[rb * 64 + ((k8 ^ (rb & 7)) << 3)];
    }
    #pragma unroll
    for (int mi = 0; mi < 4; mi++) {
      int ra = mi * 16 + fr;
      s16x8 af = *(const s16x8*)&xsT[ra * 64 + ((k8 ^ (ra & 7)) << 3)];
      #pragma unroll
      for (int ni = 0; ni < 2; ni++)
        acc[mi][ni] = __builtin_amdgcn_mfma_f32_16x16x32_bf16(af, bfv[ni], acc[mi][ni], 0, 0, 0);
    }
  }
  u16* Sc = S + ((size_t)bh * NC + c) * 8192;
  #pragma unroll
  for (int mi = 0; mi < 4; mi++) {
    #pragma unroll
    for (int ni = 0; ni < 2; ni++) {
      int p = mi * 16 + fq * 4;
      int n = w * 32 + ni * 16 + fr;
      #pragma unroll
      for (int r = 0; r < 4; r++)
        Sc[(size_t)(p + r) * 128 + n] = f2bu(acc[mi][ni][r]);
    }
  }
}

// ---------------- state passing: in-place S_c -> h_start_c (uint4/thread) ----------------
__global__ __launch_bounds__(256) void state_pass(u16* __restrict__ S,
    const float* __restrict__ Etot) {
  int bh = blockIdx.x >> 2, q = blockIdx.x & 3;
  int o = q * 2048 + threadIdx.x * 8;
  const float* Eb = Etot + (size_t)bh * NC;
  u16* base = S + (size_t)bh * NC * 8192 + o;
  float acc[8] = {0.f, 0.f, 0.f, 0.f, 0.f, 0.f, 0.f, 0.f};
  for (int c = 0; c < NC; c++) {
    uint4 sc = *(const uint4*)(base + (size_t)c * 8192);
    uint4 pre;
    pre.x = (u32)f2bu(acc[0]) | ((u32)f2bu(acc[1]) << 16);
    pre.y = (u32)f2bu(acc[2]) | ((u32)f2bu(acc[3]) << 16);
    pre.z = (u32)f2bu(acc[4]) | ((u32)f2bu(acc[5]) << 16);
    pre.w = (u32)f2bu(acc[6]) | ((u32)f2bu(acc[7]) << 16);
    *(uint4*)(base + (size_t)c * 8192) = pre;
    float E = __expf(Eb[c]);
    u32 wv[4] = {sc.x, sc.y, sc.z, sc.w};
    #pragma unroll
    for (int e = 0; e < 4; e++) {
      acc[2 * e]     = E * acc[2 * e]     + blo(wv[e]);
      acc[2 * e + 1] = E * acc[2 * e + 1] + bhi(wv[e]);
    }
  }
}

// ---------------- per-(b,c,h): inline conv+scan, G=C·B^T, mask, Yintra, Yinter, +D·x ----------------
__global__ __launch_bounds__(256) void chunk_out(const u16* __restrict__ xbc,
    const u16* __restrict__ dtraw, const u16* __restrict__ hstart,
    const float* __restrict__ dtb, const float* __restrict__ alog,
    const float* __restrict__ cw, const float* __restrict__ cb,
    const float* __restrict__ Dp, u16* __restrict__ yb) {
  __shared__ u16 Ct[64 * 128];
  __shared__ u16 Bt[64 * 128];   // Ml (64x64 swz64) overlays base after G-GEMM
  __shared__ u16 xT[64 * 64];
  __shared__ float svl[64], dtl[64], pexl[64];
  int gid = blockIdx.x;          // (b*32 + c)*32 + h
  int h = gid & 31, c = (gid >> 5) & 31, b = gid >> 10;
  int tid = threadIdx.x, w = tid >> 6, lane = tid & 63;
  int fr = lane & 15, fq = lane >> 4;
  int tb = c * 64;
  const u16* xbcb = xbc + (size_t)b * Ll * CD;
  const u16* hsrc = hstart + (((size_t)(b * 32 + h)) * NC + c) * 8192;
  int wp = w * 16, wj = w * 16;
  // h_start fragments: 4 x 16B global loads, issued early
  s16x8 h4[4];
  #pragma unroll
  for (int ks = 0; ks < 4; ks++) {
    int rb = wp + fr;
    int k8 = ks * 4 + fq;
    h4[ks] = *(const s16x8*)(hsrc + (size_t)rb * 128 + k8 * 8);
  }
  // dt scan -> LDS (wave 0)
  if (tid < 64) {
    float raw = u2f(dtraw[(size_t)(b * Ll + tb + tid) * 32 + h]);
    float v = raw + dtb[h];
    float dt = (v > 20.f) ? v : log1pf(__expf(v));
    float a = -dt * __expf(alog[h]);
    float s = wave_scan(a, tid);
    svl[tid] = s;
    pexl[tid] = __expf(s);
    dtl[tid] = dt;
  }
  // Bt / Ct / xT reg-staged with inline conv
  {
    int j = tid & 63, pg = tid >> 6;
    float o8[8];
    u16 t8[8];
    #pragma unroll
    for (int rep = 0; rep < 4; rep++) {
      int n0 = rep * 32 + pg * 8;
      int kc = n0 >> 3;
      conv8(xbcb, tb + j, 2048 + n0, cw, cb, o8);
      #pragma unroll
      for (int m = 0; m < 8; m++) t8[m] = f2bu(o8[m]);
      *(uint4*)&Bt[j * 128 + ((kc ^ (j & 7)) << 3)] = *(const uint4*)t8;
      conv8(xbcb, tb + j, 2176 + n0, cw, cb, o8);
      #pragma unroll
      for (int m = 0; m < 8; m++) t8[m] = f2bu(o8[m]);
      *(uint4*)&Ct[j * 128 + ((kc ^ (j & 7)) << 3)] = *(const uint4*)t8;
    }
    #pragma unroll
    for (int rep = 0; rep < 2; rep++) {
      int p0 = rep * 32 + pg * 8;
      conv8(xbcb, tb + j, h * 64 + p0, cw, cb, o8);
      #pragma unroll
      for (int m = 0; m < 8; m++) xT[swz64(p0 + m, j)] = f2bu(o8[m]);
    }
  }
  __syncthreads();
  // G-GEMM: G[i][j] = sum_n C[i][n]*B[j][n]
  f32x4 g2[4];
  #pragma unroll
  for (int mi = 0; mi < 4; mi++) g2[mi] = (f32x4){0.f, 0.f, 0.f, 0.f};
  #pragma unroll
  for (int ks = 0; ks < 4; ks++) {
    int k8 = ks * 4 + fq;
    int rb = wj + fr;
    s16x8 bf = *(const s16x8*)&Bt[rb * 128 + ((k8 ^ (rb & 7)) << 3)];
    #pragma unroll
    for (int mi = 0; mi < 4; mi++) {
      int ra = mi * 16 + fr;
      s16x8 af = *(const s16x8*)&Ct[ra * 128 + ((k8 ^ (ra & 7)) << 3)];
      g2[mi] = __builtin_amdgcn_mfma_f32_16x16x32_bf16(af, bf, g2[mi], 0, 0, 0);
    }
  }
  u16 mv[4][4];
  #pragma unroll
  for (int mi = 0; mi < 4; mi++) {
    int jj = wj + fr;
    #pragma unroll
    for (int r = 0; r < 4; r++) {
      int ii = mi * 16 + fq * 4 + r;
      float v = 0.f;
      if (jj <= ii) v = g2[mi][r] * __expf(svl[ii] - svl[jj]) * dtl[jj];
      mv[mi][r] = f2bu(v);
    }
  }
  __syncthreads();
  #pragma unroll
  for (int mi = 0; mi < 4; mi++) {
    int jj = wj + fr;
    #pragma unroll
    for (int r = 0; r < 4; r++) {
      int ii = mi * 16 + fq * 4 + r;
      Bt[swz64(ii, jj)] = mv[mi][r];
    }
  }
  __syncthreads();
  f32x4 aY[4], a4[4];
  #pragma unroll
  for (int mi = 0; mi < 4; mi++) { aY[mi] = (f32x4){0.f, 0.f, 0.f, 0.f}; a4[mi] = (f32x4){0.f, 0.f, 0.f, 0.f}; }
  #pragma unroll
  for (int ks = 0; ks < 2; ks++) {
    int k8 = ks * 4 + fq;
    int rb = wp + fr;
    s16x8 bf = *(const s16x8*)&xT[rb * 64 + ((k8 ^ (rb & 7)) << 3)];
    #pragma unroll
    for (int mi = 0; mi < 4; mi++) {
      int ra = mi * 16 + fr;
      s16x8 af = *(const s16x8*)&Bt[ra * 64 + ((k8 ^ (ra & 7)) << 3)];
      aY[mi] = __builtin_amdgcn_mfma_f32_16x16x32_bf16(af, bf, aY[mi], 0, 0, 0);
    }
  }
  #pragma unroll
  for (int ks = 0; ks < 4; ks++) {
    int k8 = ks * 4 + fq;
    #pragma unroll
    for (int mi = 0; mi < 4; mi++) {
      int ra = mi * 16 + fr;
      s16x8 af = *(const s16x8*)&Ct[ra * 128 + ((k8 ^ (ra & 7)) << 3)];
      a4[mi] = __builtin_amdgcn_mfma_f32_16x16x32_bf16(af, h4[ks], a4[mi], 0, 0, 0);
    }
  }
  float Dh = Dp[h];
  u16* yrow = yb + ((size_t)b * Ll + tb) * DI + h * 64;
  #pragma unroll
  for (int mi = 0; mi < 4; mi++) {
    int p = wp + fr;
    #pragma unroll
    for (int r = 0; r < 4; r++) {
      int i = mi * 16 + fq * 4 + r;
      float xh = u2f(xT[swz64(p, i)]);
      yrow[(size_t)i * DI + p] = f2bu(aY[mi][r] + pexl[i] * a4[mi][r] + Dh * xh);
    }
  }
}

// ---------------- g = y*silu(z), RMSNorm, *rms_w ----------------
__global__ __launch_bounds__(256) void gate_rms(const u16* __restrict__ y,
    const u16* __restrict__ zbuf, const float* __restrict__ rw, u16* __restrict__ g) {
  int bl = blockIdx.x, tid = threadIdx.x;
  uint4 yv = ((const uint4*)(y + (size_t)bl * DI))[tid];
  uint4 zv = ((const uint4*)(zbuf + (size_t)bl * DI))[tid];
  u32 ya[4] = {yv.x, yv.y, yv.z, yv.w};
  u32 za[4] = {zv.x, zv.y, zv.z, zv.w};
  float gv[8];
  float ss = 0.f;
  #pragma unroll
  for (int jx = 0; jx < 4; jx++) {
    float y0 = blo(ya[jx]), y1 = bhi(ya[jx]);
    float z0 = blo(za[jx]), z1 = bhi(za[jx]);
    float s0 = z0 / (1.f + __expf(-z0));
    float s1 = z1 / (1.f + __expf(-z1));
    gv[jx * 2] = y0 * s0; gv[jx * 2 + 1] = y1 * s1;
    ss += gv[jx * 2] * gv[jx * 2] + gv[jx * 2 + 1] * gv[jx * 2 + 1];
  }
  #pragma unroll
  for (int o = 32; o; o >>= 1) ss += __shfl_down(ss, o);
  __shared__ float red[4];
  int wv = tid >> 6, ln = tid & 63;
  if (ln == 0) red[wv] = ss;
  __syncthreads();
  ss = red[0] + red[1] + red[2] + red[3];
  float scale = rsqrtf(ss * (1.f / DI) + 1e-5f);
  const float* rwp = rw + tid * 8;
  ushort4 o0, o1;
  o0.x = f2bu(gv[0] * scale * rwp[0]); o0.y = f2bu(gv[1] * scale * rwp[1]);
  o0.z = f2bu(gv[2] * scale * rwp[2]); o0.w = f2bu(gv[3] * scale * rwp[3]);
  o1.x = f2bu(gv[4] * scale * rwp[4]); o1.y = f2bu(gv[5] * scale * rwp[5]);
  o1.z = f2bu(gv[6] * scale * rwp[6]); o1.w = f2bu(gv[7] * scale * rwp[7]);
  ushort4* gp = (ushort4*)(g + (size_t)bl * DI + tid * 8);
  gp[0] = o0; gp[1] = o1;
}

extern "C" void kernel_launch(void* const* d_in, const int* in_sizes, int n_in,
                              void* d_out, int out_size, void* d_ws, size_t ws_size,
                              hipStream_t stream) {
  const float* x    = (const float*)d_in[0];
  const float* lnw  = (const float*)d_in[1];
  const float* lnb  = (const float*)d_in[2];
  const float* w1   = (const float*)d_in[3];
  const float* cw   = (const float*)d_in[4];
  const float* cb   = (const float*)d_in[5];
  const float* dtb  = (const float*)d_in[6];
  const float* alog = (const float*)d_in[7];
  const float* Dp   = (const float*)d_in[8];
  const float* rw   = (const float*)d_in[9];
  const float* w2   = (const float*)d_in[10];

  // workspace layout (bytes); overlays are stream-order-safe:
  //   ub/W1b dead after in_proj; Sbuf fresh; gb overlays Sbuf (dead after chunk_out).
  char* ws = (char*)d_ws;
  u16*   ub     = (u16*)(ws + 0);            // 16,777,216
  u16*   W1b    = (u16*)(ws + 16777216);     // 9,175,040  (ends 25,952,256)
  u16*   dtraw  = (u16*)(ws + 26214400);     // 524,288    (ends 26,738,688)
  u16*   zbuf   = (u16*)(ws + 27262976);     // 33,554,432 (ends 60,817,408)
  u16*   xbc    = (u16*)(ws + 60817408);     // 37,748,736 (ends 98,566,144)
  u16*   Sbuf   = (u16*)(ws + 98566144);     // 67,108,864 (ends 165,675,008)
  u16*   gb     = (u16*)(ws + 98566144);     // 33,554,432 (overlays Sbuf)
  u16*   yb     = (u16*)(ws + 165675008);    // 33,554,432 (ends 199,229,440)
  u16*   W2b    = (u16*)(ws + 199229440);    // 4,194,304  (ends 203,423,744)
  float* Etot   = (float*)(ws + 203423744);  // 16,384     (ends 203,440,128)
  if (ws_size < 203440128u) return;

  float* out = (float*)d_out;

  int cvt_blocks = (NP_PAD * 1024 + 1024 * 2048) / 256;   // 26112
  prep_kernel<<<BL + cvt_blocks, 256, 0, stream>>>(x, lnw, lnb, ub, w1, W1b, w2, W2b);
  gemm2p<0><<<1120, 512, 0, stream>>>(ub, W1b, zbuf, xbc, dtraw, nullptr);
  chunk_state<<<4096, 256, 0, stream>>>(xbc, dtraw, dtb, alog, cw, cb, Sbuf, Etot);
  state_pass<<<512, 256, 0, stream>>>(Sbuf, Etot);
  chunk_out<<<4096, 256, 0, stream>>>(xbc, dtraw, Sbuf, dtb, alog, cw, cb, Dp, yb);
  gate_rms<<<BL, 256, 0, stream>>>(yb, zbuf, rw, gb);
  gemm2p<1><<<256, 512, 0, stream>>>(gb, W2b, out, nullptr, nullptr, x);
}

// Round 13
// 312.282 us; speedup vs baseline: 1.3912x; 1.3912x over previous
//
#include <hip/hip_runtime.h>
#include <hip/hip_bf16.h>

#define DEV __device__ __forceinline__

typedef unsigned short u16;
typedef unsigned int u32;
typedef float f32x4 __attribute__((ext_vector_type(4)));
typedef short s16x8 __attribute__((ext_vector_type(8)));

static constexpr int Bb = 4, Ll = 2048, DM = 1024, DI = 2048, NH = 32;
static constexpr int CD = 2304;       // conv dim
static constexpr int NP = 4384;       // d_in_proj
static constexpr int NP_PAD = 4480;   // 35*128
static constexpr int BL = Bb * Ll;    // 8192
static constexpr int NC = 32;         // chunks per sequence (L/64)

DEV float u2f(u16 s) { return __uint_as_float(((u32)s) << 16); }
DEV u16 f2bu(float f) {
  __hip_bfloat16 h = __float2bfloat16(f);
  u16 s; __builtin_memcpy(&s, &h, 2); return s;
}
DEV float blo(u32 u) { return __uint_as_float(u << 16); }
DEV float bhi(u32 u) { return __uint_as_float(u & 0xffff0000u); }

// XOR-swizzled LDS index for [rows][64] bf16 tiles (k-minor).
DEV int swz64(int r, int k)  { return r * 64  + ((((k >> 3) ^ (r & 7))) << 3) + (k & 7); }

DEV void gl_lds16(const u16* g, u16* l) {
  __builtin_amdgcn_global_load_lds(
      (const __attribute__((address_space(1))) u32*)g,
      (__attribute__((address_space(3))) u32*)l, 16, 0, 0);
}

// ---------------- prep: LayerNorm (blocks 0..8191) + weight cvt (rest) ----------------
__global__ __launch_bounds__(256) void prep_kernel(const float* __restrict__ x,
    const float* __restrict__ w, const float* __restrict__ bia, u16* __restrict__ u,
    const float* __restrict__ w1, u16* __restrict__ W1b,
    const float* __restrict__ w2, u16* __restrict__ W2b) {
  __shared__ float rs[4], rs2[4];
  int tid = threadIdx.x;
  if (blockIdx.x < BL) {
    int row = blockIdx.x;
    const float4* xr = (const float4*)(x + (size_t)row * DM);
    float4 v = xr[tid];
    float s = v.x + v.y + v.z + v.w;
    float s2 = v.x*v.x + v.y*v.y + v.z*v.z + v.w*v.w;
    #pragma unroll
    for (int o = 32; o; o >>= 1) { s += __shfl_down(s, o); s2 += __shfl_down(s2, o); }
    int wv = tid >> 6, ln = tid & 63;
    if (ln == 0) { rs[wv] = s; rs2[wv] = s2; }
    __syncthreads();
    s = rs[0] + rs[1] + rs[2] + rs[3];
    s2 = rs2[0] + rs2[1] + rs2[2] + rs2[3];
    float mu = s * (1.f / DM);
    float var = s2 * (1.f / DM) - mu * mu;
    float inv = rsqrtf(var + 1e-5f);
    float4 wv4 = ((const float4*)w)[tid], bv4 = ((const float4*)bia)[tid];
    ushort4 o;
    o.x = f2bu((v.x - mu) * inv * wv4.x + bv4.x);
    o.y = f2bu((v.y - mu) * inv * wv4.y + bv4.y);
    o.z = f2bu((v.z - mu) * inv * wv4.z + bv4.z);
    o.w = f2bu((v.w - mu) * inv * wv4.w + bv4.w);
    ((ushort4*)(u + (size_t)row * DM))[tid] = o;
  } else {
    const int total1 = NP_PAD * 1024;
    int i = (blockIdx.x - BL) * 256 + tid;
    if (i < total1) {
      int r = i >> 10;
      W1b[i] = (r < NP) ? f2bu(w1[i]) : (u16)0;
    } else {
      int j = i - total1;
      if (j < 1024 * 2048) W2b[j] = f2bu(w2[j]);
    }
  }
}

// ============ 256x128 2-phase swizzled GEMM, counted-vmcnt prefetch ============
// C[m][n] = sum_k A[m][k]*Bw[n][k].
// MODE 0: K=1024, split bf16 epilogue (zbuf/xbc/dtraw). MODE 1: K=2048, f32+resid.
template<int MODE>
__global__ __launch_bounds__(512, 4) void gemm2p(const u16* __restrict__ A,
    const u16* __restrict__ Bw, void* __restrict__ o0, u16* __restrict__ xbc,
    u16* __restrict__ dtraw, const float* __restrict__ resid) {
  constexpr int K = (MODE == 0) ? 1024 : 2048;
  constexpr int NT = K / 32;
  __shared__ u16 SH[24576];
  int tid = threadIdx.x, wid = tid >> 6, lane = tid & 63;
  int fr = lane & 15, fq = lane >> 4;
  int nb = blockIdx.x;
  int xcd = nb & 7, i = nb >> 3;
  int m0 = (xcd * 4 + (i & 3)) * 256;
  int n0 = (i >> 2) * 128;
  int wm = (wid >> 1) * 64, wn = (wid & 1) * 64;
  int ksrcE = (((lane & 3) ^ ((lane >> 3) & 3)) << 3);
  int lr = lane >> 2;

  f32x4 acc[4][4];
  #pragma unroll
  for (int a = 0; a < 4; a++)
    #pragma unroll
    for (int b = 0; b < 4; b++) acc[a][b] = (f32x4){0.f, 0.f, 0.f, 0.f};

  auto STGA = [&](int t, int dstE) {
    #pragma unroll
    for (int h = 0; h < 2; h++) {
      int r0 = h * 128 + wid * 16;
      gl_lds16(A + (size_t)(m0 + r0 + lr) * K + t * 32 + ksrcE, &SH[dstE + r0 * 32]);
    }
  };
  auto STGB = [&](int t, int dstE) {
    int r0 = wid * 16;
    gl_lds16(Bw + (size_t)(n0 + r0 + lr) * K + t * 32 + ksrcE, &SH[dstE + r0 * 32]);
  };

  STGA(0, 0);
  STGB(0, 16384);
  asm volatile("s_waitcnt vmcnt(0)\n\ts_barrier" ::: "memory");
  for (int t = 0; t < NT; t++) {
    int ca = (t & 1) * 8192, cbf = 16384 + (t & 1) * 4096;
    if (t < NT - 1) {
      STGA(t + 1, ((t + 1) & 1) * 8192);
      STGB(t + 1, 16384 + ((t + 1) & 1) * 4096);
      asm volatile("s_waitcnt vmcnt(3)\n\ts_barrier" ::: "memory");
    } else {
      asm volatile("s_waitcnt vmcnt(0)\n\ts_barrier" ::: "memory");
    }
    s16x8 bB[4];
    #pragma unroll
    for (int nf = 0; nf < 4; nf++) {
      int rb = wn + nf * 16 + fr;
      bB[nf] = *(const s16x8*)&SH[cbf + rb * 32 + ((fq ^ ((rb >> 1) & 3)) << 3)];
    }
    __builtin_amdgcn_s_setprio(1);
    #pragma unroll
    for (int mf = 0; mf < 4; mf++) {
      int ra = wm + mf * 16 + fr;
      s16x8 af = *(const s16x8*)&SH[ca + ra * 32 + ((fq ^ ((ra >> 1) & 3)) << 3)];
      #pragma unroll
      for (int nf = 0; nf < 4; nf++)
        acc[mf][nf] = __builtin_amdgcn_mfma_f32_16x16x32_bf16(af, bB[nf], acc[mf][nf], 0, 0, 0);
    }
    __builtin_amdgcn_s_setprio(0);
    asm volatile("s_barrier" ::: "memory");
  }
  // epilogue
  if (MODE == 0) {
    u16* zbuf = (u16*)o0;
    #pragma unroll
    for (int mf = 0; mf < 4; mf++) {
      #pragma unroll
      for (int nf = 0; nf < 4; nf++) {
        int col = n0 + wn + nf * 16 + fr;
        #pragma unroll
        for (int r = 0; r < 4; r++) {
          int row = m0 + wm + mf * 16 + fq * 4 + r;
          float v = acc[mf][nf][r];
          if (col < 2048)       zbuf[(size_t)row * 2048 + col] = f2bu(v);
          else if (col < 4352)  xbc[(size_t)row * 2304 + (col - 2048)] = f2bu(v);
          else if (col < 4384)  dtraw[(size_t)row * 32 + (col - 4352)] = f2bu(v);
        }
      }
    }
  } else {
    float* of = (float*)o0;
    #pragma unroll
    for (int mf = 0; mf < 4; mf++) {
      #pragma unroll
      for (int nf = 0; nf < 4; nf++) {
        int col = n0 + wn + nf * 16 + fr;
        #pragma unroll
        for (int r = 0; r < 4; r++) {
          int row = m0 + wm + mf * 16 + fq * 4 + r;
          of[(size_t)row * 1024 + col] = acc[mf][nf][r] + resid[(size_t)row * 1024 + col];
        }
      }
    }
  }
}

// ---------------- conv+SiLU (blocks 0..9215) + dt/cumsum (rest) ----------------
__global__ __launch_bounds__(256) void convdt_kernel(const u16* __restrict__ xbc,
    const float* __restrict__ cw, const float* __restrict__ cb, u16* __restrict__ out,
    const u16* __restrict__ dtraw, const float* __restrict__ dtb,
    const float* __restrict__ alog, float* __restrict__ dtv, float* __restrict__ sv) {
  const int CONV_BLOCKS = (BL * (CD / 8)) / 256;   // 9216
  if (blockIdx.x < CONV_BLOCKS) {
    int i = blockIdx.x * 256 + threadIdx.x;
    int c8 = i % (CD / 8);
    int bl = i / (CD / 8);
    int l = bl & (Ll - 1);
    int c0 = c8 * 8;
    uint4 R[4];
    #pragma unroll
    for (int k = 0; k < 4; k++) {
      int ls = l - 3 + k;
      if (ls >= 0) R[k] = *(const uint4*)(xbc + (size_t)(bl - 3 + k) * CD + c0);
      else         R[k] = (uint4){0u, 0u, 0u, 0u};
    }
    u16 o[8];
    #pragma unroll
    for (int e = 0; e < 8; e++) {
      float acc = cb[c0 + e];
      float4 wv = *(const float4*)(cw + (size_t)(c0 + e) * 4);
      float wk[4] = {wv.x, wv.y, wv.z, wv.w};
      #pragma unroll
      for (int k = 0; k < 4; k++) {
        u32 word = (&R[k].x)[e >> 1];
        float xv = (e & 1) ? bhi(word) : blo(word);
        acc += wk[k] * xv;
      }
      float sg = 1.f / (1.f + __expf(-acc));
      o[e] = f2bu(acc * sg);
    }
    uint4 ov;
    ov.x = (u32)o[0] | ((u32)o[1] << 16);
    ov.y = (u32)o[2] | ((u32)o[3] << 16);
    ov.z = (u32)o[4] | ((u32)o[5] << 16);
    ov.w = (u32)o[6] | ((u32)o[7] << 16);
    *(uint4*)(out + (size_t)bl * CD + c0) = ov;
  } else {
    int wid = threadIdx.x >> 6, lane = threadIdx.x & 63;
    int g = (blockIdx.x - CONV_BLOCKS) * 4 + wid;   // (b,h,c), 4096 total
    int b = g >> 10, h = (g >> 5) & 31, c = g & 31;
    int t = c * 64 + lane;
    float raw = u2f(dtraw[(size_t)(b * Ll + t) * 32 + h]);
    float v = raw + dtb[h];
    float dt = (v > 20.f) ? v : log1pf(__expf(v));
    float a = -dt * __expf(alog[h]);
    float s = a;
    #pragma unroll
    for (int o = 1; o < 64; o <<= 1) {
      float u = __shfl_up(s, o);
      if (lane >= o) s += u;
    }
    int idx = (b * 32 + h) * Ll + t;
    dtv[idx] = dt;
    sv[idx] = s;
  }
}

// ---------------- per-(b,c,h): chunk-state GEMM -> S_c[p][n] (bf16) ----------------
__global__ __launch_bounds__(256) void chunk_state(const u16* __restrict__ conv,
    const float* __restrict__ dtv, const float* __restrict__ sv,
    u16* __restrict__ S) {
  __shared__ u16 xsT[64 * 64];   // [p][j] swizzled, scaled
  __shared__ u16 BT[128 * 64];   // [n][j] swizzled
  int gid = blockIdx.x;          // (b*32 + c)*32 + h
  int h = gid & 31, c = (gid >> 5) & 31, b = gid >> 10;
  int bh = b * 32 + h;
  int tid = threadIdx.x, w = tid >> 6, lane = tid & 63;
  int fr = lane & 15, fq = lane >> 4;
  int j = tid & 63, pg = tid >> 6;
  int tb = c * 64;
  const float* svb = sv + (size_t)bh * Ll + tb;
  const float* dvb = dtv + (size_t)bh * Ll + tb;
  const u16* cvb = conv + (size_t)(b * Ll + tb) * CD;
  float s_last = svb[63];
  float wj = __expf(s_last - svb[j]) * dvb[j];
  const u16* rowp = cvb + (size_t)j * CD;
  #pragma unroll
  for (int rep = 0; rep < 2; rep++) {
    int p0 = rep * 32 + pg * 8;
    uint4 v = *(const uint4*)(rowp + h * 64 + p0);
    u32 va[4] = {v.x, v.y, v.z, v.w};
    #pragma unroll
    for (int e = 0; e < 4; e++) {
      xsT[swz64(p0 + 2 * e, j)]     = f2bu(blo(va[e]) * wj);
      xsT[swz64(p0 + 2 * e + 1, j)] = f2bu(bhi(va[e]) * wj);
    }
  }
  #pragma unroll
  for (int rep = 0; rep < 4; rep++) {
    int n0 = rep * 32 + pg * 8;
    uint4 v = *(const uint4*)(rowp + DI + n0);
    u32 va[4] = {v.x, v.y, v.z, v.w};
    #pragma unroll
    for (int e = 0; e < 4; e++) {
      BT[swz64(n0 + 2 * e, j)]     = (u16)(va[e] & 0xffffu);
      BT[swz64(n0 + 2 * e + 1, j)] = (u16)(va[e] >> 16);
    }
  }
  __syncthreads();
  f32x4 acc[4][2];
  #pragma unroll
  for (int mi = 0; mi < 4; mi++)
    #pragma unroll
    for (int ni = 0; ni < 2; ni++) acc[mi][ni] = (f32x4){0.f, 0.f, 0.f, 0.f};
  #pragma unroll
  for (int ks = 0; ks < 2; ks++) {
    int k8 = ks * 4 + fq;
    s16x8 bfv[2];
    #pragma unroll
    for (int ni = 0; ni < 2; ni++) {
      int rb = w * 32 + ni * 16 + fr;
      bfv[ni] = *(const s16x8*)&BT[rb * 64 + ((k8 ^ (rb & 7)) << 3)];
    }
    #pragma unroll
    for (int mi = 0; mi < 4; mi++) {
      int ra = mi * 16 + fr;
      s16x8 af = *(const s16x8*)&xsT[ra * 64 + ((k8 ^ (ra & 7)) << 3)];
      #pragma unroll
      for (int ni = 0; ni < 2; ni++)
        acc[mi][ni] = __builtin_amdgcn_mfma_f32_16x16x32_bf16(af, bfv[ni], acc[mi][ni], 0, 0, 0);
    }
  }
  u16* Sc = S + ((size_t)bh * NC + c) * 8192;
  #pragma unroll
  for (int mi = 0; mi < 4; mi++) {
    #pragma unroll
    for (int ni = 0; ni < 2; ni++) {
      int p = mi * 16 + fq * 4;
      int n = w * 32 + ni * 16 + fr;
      #pragma unroll
      for (int r = 0; r < 4; r++)
        Sc[(size_t)(p + r) * 128 + n] = f2bu(acc[mi][ni][r]);
    }
  }
}

// ---------------- state passing: in-place S_c -> h_start_c (uint4/thread) ----------------
__global__ __launch_bounds__(256) void state_pass(u16* __restrict__ S,
    const float* __restrict__ sv) {
  int bh = blockIdx.x >> 2, q = blockIdx.x & 3;
  int o = q * 2048 + threadIdx.x * 8;
  const float* svb = sv + (size_t)bh * Ll;
  u16* base = S + (size_t)bh * NC * 8192 + o;
  float acc[8] = {0.f, 0.f, 0.f, 0.f, 0.f, 0.f, 0.f, 0.f};
  for (int c = 0; c < NC; c++) {
    uint4 sc = *(const uint4*)(base + (size_t)c * 8192);
    uint4 pre;
    pre.x = (u32)f2bu(acc[0]) | ((u32)f2bu(acc[1]) << 16);
    pre.y = (u32)f2bu(acc[2]) | ((u32)f2bu(acc[3]) << 16);
    pre.z = (u32)f2bu(acc[4]) | ((u32)f2bu(acc[5]) << 16);
    pre.w = (u32)f2bu(acc[6]) | ((u32)f2bu(acc[7]) << 16);
    *(uint4*)(base + (size_t)c * 8192) = pre;
    float E = __expf(svb[c * 64 + 63]);
    u32 wv[4] = {sc.x, sc.y, sc.z, sc.w};
    #pragma unroll
    for (int e = 0; e < 4; e++) {
      acc[2 * e]     = E * acc[2 * e]     + blo(wv[e]);
      acc[2 * e + 1] = E * acc[2 * e + 1] + bhi(wv[e]);
    }
  }
}

// ---------------- per-(b,c,h): G=C·B^T, mask, Yintra=M·x, Yinter=exp(s)·(C·h^T), +D·x ----------------
// h_start read direct from global (L2-hot) into regs; Ml overlays Bt (dead after G-GEMM).
__global__ __launch_bounds__(256) void chunk_out(const u16* __restrict__ conv,
    const u16* __restrict__ hstart, const float* __restrict__ dtv,
    const float* __restrict__ sv, const float* __restrict__ Dp,
    u16* __restrict__ yb) {
  __shared__ u16 Ct[64 * 128];
  __shared__ u16 Bt[64 * 128];   // Ml (64x64 swz64, 8KB) overlays base after G-GEMM
  __shared__ u16 xT[64 * 64];
  __shared__ float svl[64], dtl[64], pexl[64];
  int gid = blockIdx.x;          // (b*32 + c)*32 + h
  int h = gid & 31, c = (gid >> 5) & 31, b = gid >> 10;
  int tid = threadIdx.x, w = tid >> 6, lane = tid & 63;
  int fr = lane & 15, fq = lane >> 4;
  int tb = c * 64;
  const u16* cvb = conv + ((size_t)b * Ll + tb) * CD;
  const u16* hsrc = hstart + (((size_t)(b * 32 + h)) * NC + c) * 8192;
  int wp = w * 16, wj = w * 16;
  // h_start fragments: 4 x 16B global loads, issued early (hide under GEMMs)
  s16x8 h4[4];
  #pragma unroll
  for (int ks = 0; ks < 4; ks++) {
    int rb = wp + fr;
    int k8 = ks * 4 + fq;
    h4[ks] = *(const s16x8*)(hsrc + (size_t)rb * 128 + k8 * 8);
  }
  #pragma unroll
  for (int qq = 0; qq < 4; qq++) {
    int q = w * 4 + qq;
    int i = q * 4 + (lane >> 4);
    int s = lane & 15;
    int kc = ((s ^ (i & 7)) << 3);
    gl_lds16(cvb + (size_t)i * CD + 2176 + kc, &Ct[q * 512]);
    gl_lds16(cvb + (size_t)i * CD + 2048 + kc, &Bt[q * 512]);
  }
  {
    int j = tid & 63, pg = tid >> 6;
    const u16* rowp = cvb + (size_t)j * CD + h * 64;
    #pragma unroll
    for (int rep = 0; rep < 2; rep++) {
      int p0 = rep * 32 + pg * 8;
      uint4 v = *(const uint4*)(rowp + p0);
      u32 va[4] = {v.x, v.y, v.z, v.w};
      #pragma unroll
      for (int e = 0; e < 4; e++) {
        xT[swz64(p0 + 2 * e, j)]     = (u16)(va[e] & 0xffffu);
        xT[swz64(p0 + 2 * e + 1, j)] = (u16)(va[e] >> 16);
      }
    }
  }
  if (tid < 64) {
    float s = sv[(size_t)(b * 32 + h) * Ll + tb + tid];
    svl[tid] = s;
    pexl[tid] = __expf(s);
    dtl[tid] = dtv[(size_t)(b * 32 + h) * Ll + tb + tid];
  }
  __syncthreads();
  // G-GEMM: G[i][j] = sum_n C[i][n]*B[j][n]; wave owns j-slice of 16
  f32x4 g2[4];
  #pragma unroll
  for (int mi = 0; mi < 4; mi++) g2[mi] = (f32x4){0.f, 0.f, 0.f, 0.f};
  #pragma unroll
  for (int ks = 0; ks < 4; ks++) {
    int k8 = ks * 4 + fq;
    int rb = wj + fr;
    s16x8 bf = *(const s16x8*)&Bt[rb * 128 + ((k8 ^ (rb & 7)) << 3)];
    #pragma unroll
    for (int mi = 0; mi < 4; mi++) {
      int ra = mi * 16 + fr;
      s16x8 af = *(const s16x8*)&Ct[ra * 128 + ((k8 ^ (ra & 7)) << 3)];
      g2[mi] = __builtin_amdgcn_mfma_f32_16x16x32_bf16(af, bf, g2[mi], 0, 0, 0);
    }
  }
  // mask+scale in regs
  u16 mv[4][4];
  #pragma unroll
  for (int mi = 0; mi < 4; mi++) {
    int jj = wj + fr;
    #pragma unroll
    for (int r = 0; r < 4; r++) {
      int ii = mi * 16 + fq * 4 + r;
      float v = 0.f;
      if (jj <= ii) v = g2[mi][r] * __expf(svl[ii] - svl[jj]) * dtl[jj];
      mv[mi][r] = f2bu(v);
    }
  }
  __syncthreads();   // all G-GEMM reads of Bt complete
  #pragma unroll
  for (int mi = 0; mi < 4; mi++) {
    int jj = wj + fr;
    #pragma unroll
    for (int r = 0; r < 4; r++) {
      int ii = mi * 16 + fq * 4 + r;
      Bt[swz64(ii, jj)] = mv[mi][r];   // Ml over Bt base
    }
  }
  __syncthreads();
  // GEMM-3 (Ml·x, K=64) and GEMM-4 (C·h^T via h4 regs, K=128)
  f32x4 aY[4], a4[4];
  #pragma unroll
  for (int mi = 0; mi < 4; mi++) { aY[mi] = (f32x4){0.f, 0.f, 0.f, 0.f}; a4[mi] = (f32x4){0.f, 0.f, 0.f, 0.f}; }
  #pragma unroll
  for (int ks = 0; ks < 2; ks++) {
    int k8 = ks * 4 + fq;
    int rb = wp + fr;
    s16x8 bf = *(const s16x8*)&xT[rb * 64 + ((k8 ^ (rb & 7)) << 3)];
    #pragma unroll
    for (int mi = 0; mi < 4; mi++) {
      int ra = mi * 16 + fr;
      s16x8 af = *(const s16x8*)&Bt[ra * 64 + ((k8 ^ (ra & 7)) << 3)];
      aY[mi] = __builtin_amdgcn_mfma_f32_16x16x32_bf16(af, bf, aY[mi], 0, 0, 0);
    }
  }
  #pragma unroll
  for (int ks = 0; ks < 4; ks++) {
    int k8 = ks * 4 + fq;
    #pragma unroll
    for (int mi = 0; mi < 4; mi++) {
      int ra = mi * 16 + fr;
      s16x8 af = *(const s16x8*)&Ct[ra * 128 + ((k8 ^ (ra & 7)) << 3)];
      a4[mi] = __builtin_amdgcn_mfma_f32_16x16x32_bf16(af, h4[ks], a4[mi], 0, 0, 0);
    }
  }
  float Dh = Dp[h];
  u16* yrow = yb + ((size_t)b * Ll + tb) * DI + h * 64;
  #pragma unroll
  for (int mi = 0; mi < 4; mi++) {
    int p = wp + fr;
    #pragma unroll
    for (int r = 0; r < 4; r++) {
      int i = mi * 16 + fq * 4 + r;
      float xh = u2f(xT[swz64(p, i)]);
      yrow[(size_t)i * DI + p] = f2bu(aY[mi][r] + pexl[i] * a4[mi][r] + Dh * xh);
    }
  }
}

// ---------------- g = y*silu(z), RMSNorm, *rms_w ----------------
__global__ __launch_bounds__(256) void gate_rms(const u16* __restrict__ y,
    const u16* __restrict__ zbuf, const float* __restrict__ rw, u16* __restrict__ g) {
  int bl = blockIdx.x, tid = threadIdx.x;
  uint4 yv = ((const uint4*)(y + (size_t)bl * DI))[tid];
  uint4 zv = ((const uint4*)(zbuf + (size_t)bl * DI))[tid];
  u32 ya[4] = {yv.x, yv.y, yv.z, yv.w};
  u32 za[4] = {zv.x, zv.y, zv.z, zv.w};
  float gv[8];
  float ss = 0.f;
  #pragma unroll
  for (int jx = 0; jx < 4; jx++) {
    float y0 = blo(ya[jx]), y1 = bhi(ya[jx]);
    float z0 = blo(za[jx]), z1 = bhi(za[jx]);
    float s0 = z0 / (1.f + __expf(-z0));
    float s1 = z1 / (1.f + __expf(-z1));
    gv[jx * 2] = y0 * s0; gv[jx * 2 + 1] = y1 * s1;
    ss += gv[jx * 2] * gv[jx * 2] + gv[jx * 2 + 1] * gv[jx * 2 + 1];
  }
  #pragma unroll
  for (int o = 32; o; o >>= 1) ss += __shfl_down(ss, o);
  __shared__ float red[4];
  int wv = tid >> 6, ln = tid & 63;
  if (ln == 0) red[wv] = ss;
  __syncthreads();
  ss = red[0] + red[1] + red[2] + red[3];
  float scale = rsqrtf(ss * (1.f / DI) + 1e-5f);
  float4 rw0 = *(const float4*)(rw + tid * 8);
  float4 rw1 = *(const float4*)(rw + tid * 8 + 4);
  ushort4 o0, o1;
  o0.x = f2bu(gv[0] * scale * rw0.x); o0.y = f2bu(gv[1] * scale * rw0.y);
  o0.z = f2bu(gv[2] * scale * rw0.z); o0.w = f2bu(gv[3] * scale * rw0.w);
  o1.x = f2bu(gv[4] * scale * rw1.x); o1.y = f2bu(gv[5] * scale * rw1.y);
  o1.z = f2bu(gv[6] * scale * rw1.z); o1.w = f2bu(gv[7] * scale * rw1.w);
  ushort4* gp = (ushort4*)(g + (size_t)bl * DI + tid * 8);
  gp[0] = o0; gp[1] = o1;
}

extern "C" void kernel_launch(void* const* d_in, const int* in_sizes, int n_in,
                              void* d_out, int out_size, void* d_ws, size_t ws_size,
                              hipStream_t stream) {
  const float* x    = (const float*)d_in[0];
  const float* lnw  = (const float*)d_in[1];
  const float* lnb  = (const float*)d_in[2];
  const float* w1   = (const float*)d_in[3];
  const float* cw   = (const float*)d_in[4];
  const float* cb   = (const float*)d_in[5];
  const float* dtb  = (const float*)d_in[6];
  const float* alog = (const float*)d_in[7];
  const float* Dp   = (const float*)d_in[8];
  const float* rw   = (const float*)d_in[9];
  const float* w2   = (const float*)d_in[10];

  // workspace layout (bytes); overlays are stream-order-safe.
  char* ws = (char*)d_ws;
  u16*   ub     = (u16*)(ws + 0);            // 16,777,216
  u16*   W1b    = (u16*)(ws + 16777216);     // 9,175,040
  u16*   conv   = (u16*)(ws + 0);            // 37,748,736 (overlays ub+W1b after in_proj)
  u16*   zbuf   = (u16*)(ws + 37748736);     // 33,554,432
  u16*   xbc    = (u16*)(ws + 71303168);     // 37,748,736
  u16*   dtraw  = (u16*)(ws + 109051904);    // 524,288
  u16*   Sbuf   = (u16*)(ws + 71303168);     // 67,108,864 (overlays xbc+dtraw)
  u16*   gb     = (u16*)(ws + 71303168);     // 33,554,432 (overlays Sbuf)
  float* dtv    = (float*)(ws + 138412032);  // 1,048,576
  float* sv     = (float*)(ws + 139460608);  // 1,048,576
  u16*   yb     = (u16*)(ws + 140509184);    // 33,554,432
  u16*   W2b    = (u16*)(ws + 174063616);    // 4,194,304 -> end 178,257,920
  if (ws_size < 178257920u) return;

  float* out = (float*)d_out;

  int cvt_blocks = (NP_PAD * 1024 + 1024 * 2048) / 256;   // 26112
  prep_kernel<<<BL + cvt_blocks, 256, 0, stream>>>(x, lnw, lnb, ub, w1, W1b, w2, W2b);
  gemm2p<0><<<1120, 512, 0, stream>>>(ub, W1b, zbuf, xbc, dtraw, nullptr);
  convdt_kernel<<<(BL * (CD / 8)) / 256 + 1024, 256, 0, stream>>>(
      xbc, cw, cb, conv, dtraw, dtb, alog, dtv, sv);
  chunk_state<<<4096, 256, 0, stream>>>(conv, dtv, sv, Sbuf);
  state_pass<<<512, 256, 0, stream>>>(Sbuf, sv);
  chunk_out<<<4096, 256, 0, stream>>>(conv, Sbuf, dtv, sv, Dp, yb);
  gate_rms<<<BL, 256, 0, stream>>>(yb, zbuf, rw, gb);
  gemm2p<1><<<256, 512, 0, stream>>>(gb, W2b, out, nullptr, nullptr, x);
}